// Round 1
// baseline (444.831 us; speedup 1.0000x reference)
//
#include <hip/hip_runtime.h>

#define IMG_W 1024
#define BATCH 32

// ---------------------------------------------------------------------------
// Kernel X: inclusive cumsum along width (channel 0).
// One wave (64 lanes) per row. Lane l owns 16 contiguous floats [16l, 16l+16).
// Local serial scan -> wave exclusive scan of lane totals via shfl_up -> store.
// ---------------------------------------------------------------------------
__global__ __launch_bounds__(256) void cumsum_x_kernel(const float* __restrict__ in,
                                                       float* __restrict__ out) {
    const int lane = threadIdx.x & 63;
    const int wave = threadIdx.x >> 6;
    const int row  = blockIdx.x * 4 + wave;          // 0 .. BATCH*IMG_W-1
    const int b    = row >> 10;                      // row / IMG_W
    const int y    = row & (IMG_W - 1);

    const size_t base = (size_t)b * (2 * IMG_W * IMG_W) + (size_t)y * IMG_W; // channel 0
    const float4* ip = (const float4*)(in + base) + lane * 4;
    float4*       op = (float4*)(out + base) + lane * 4;

    float4 a0 = ip[0];
    float4 a1 = ip[1];
    float4 a2 = ip[2];
    float4 a3 = ip[3];

    float v[16];
    v[0] = a0.x; v[1] = a0.y; v[2]  = a0.z; v[3]  = a0.w;
    v[4] = a1.x; v[5] = a1.y; v[6]  = a1.z; v[7]  = a1.w;
    v[8] = a2.x; v[9] = a2.y; v[10] = a2.z; v[11] = a2.w;
    v[12] = a3.x; v[13] = a3.y; v[14] = a3.z; v[15] = a3.w;

    #pragma unroll
    for (int i = 1; i < 16; ++i) v[i] += v[i - 1];

    // Exclusive wave-wide prefix of per-lane totals.
    const float tot = v[15];
    float s = tot;
    #pragma unroll
    for (int d = 1; d < 64; d <<= 1) {
        float n = __shfl_up(s, d);
        if (lane >= d) s += n;
    }
    const float excl = s - tot;

    #pragma unroll
    for (int i = 0; i < 16; ++i) v[i] += excl;

    op[0] = make_float4(v[0],  v[1],  v[2],  v[3]);
    op[1] = make_float4(v[4],  v[5],  v[6],  v[7]);
    op[2] = make_float4(v[8],  v[9],  v[10], v[11]);
    op[3] = make_float4(v[12], v[13], v[14], v[15]);
}

// ---------------------------------------------------------------------------
// Kernel Y: inclusive cumsum along height (channel 1).
// Block = 1024 threads = 32 columns x 32 segments (32 rows each, full height).
// Thread (c = tid&31, s = tid>>5): reads its 32-row column segment directly
// from global (per instruction: 2 x 128B contiguous lines -> coalesced),
// keeps segment cumsum in registers, shares segment totals via 4 KiB LDS,
// adds exclusive offset, writes back with the same coalesced pattern.
// ---------------------------------------------------------------------------
__global__ __launch_bounds__(1024) void cumsum_y_kernel(const float* __restrict__ in,
                                                        float* __restrict__ out) {
    __shared__ float aux[32 * 32];

    const int c = threadIdx.x & 31;   // column within block
    const int s = threadIdx.x >> 5;   // segment (0..31), 32 rows each

    const int col_g = blockIdx.x * 32 + c;      // global column 0 .. BATCH*IMG_W-1
    const int b     = col_g >> 10;
    const int x     = col_g & (IMG_W - 1);

    const size_t base = (size_t)b * (2 * IMG_W * IMG_W) + (size_t)(IMG_W * IMG_W) // channel 1
                      + (size_t)x + (size_t)(s * 32) * IMG_W;

    const float* ip = in + base;
    float*       op = out + base;

    float v[32];
    float acc = 0.0f;
    #pragma unroll
    for (int i = 0; i < 32; ++i) {
        acc += ip[(size_t)i * IMG_W];
        v[i] = acc;
    }

    aux[s * 32 + c] = acc;
    __syncthreads();

    // Exclusive prefix over segments for this column. Uniform loop; rows of
    // aux are broadcast (lanes 0-31 and 32-63 read identical addresses).
    float off = 0.0f;
    #pragma unroll
    for (int t = 0; t < 31; ++t) {
        const float tv = aux[t * 32 + c];
        off += (t < s) ? tv : 0.0f;
    }

    #pragma unroll
    for (int i = 0; i < 32; ++i) {
        op[(size_t)i * IMG_W] = v[i] + off;
    }
}

extern "C" void kernel_launch(void* const* d_in, const int* in_sizes, int n_in,
                              void* d_out, int out_size, void* d_ws, size_t ws_size,
                              hipStream_t stream) {
    const float* in  = (const float*)d_in[0];
    float*       out = (float*)d_out;

    // Channel 0: width cumsum. BATCH*IMG_W rows, 4 rows (waves) per block.
    cumsum_x_kernel<<<dim3((BATCH * IMG_W) / 4), dim3(256), 0, stream>>>(in, out);

    // Channel 1: height cumsum. BATCH*IMG_W columns, 32 columns per block.
    cumsum_y_kernel<<<dim3((BATCH * IMG_W) / 32), dim3(1024), 0, stream>>>(in, out);
}

// Round 8
// 436.381 us; speedup vs baseline: 1.0194x; 1.0194x over previous
//
#include <hip/hip_runtime.h>

#define IMG_W 1024
#define BATCH 32

// Fused kernel: grid = [0,1024) Y-blocks (height cumsum, channel 1)
//               [1024,3072) X-blocks (width cumsum, channel 0)
// 1024 threads per block. Y-blocks are heavy (32 rows/thread), scheduled
// first so the short X-blocks backfill the tail.
__global__ __launch_bounds__(1024) void sgi_fused_kernel(const float* __restrict__ in,
                                                         float* __restrict__ out) {
    __shared__ float aux[32 * 32];

    const int bid = blockIdx.x;

    if (bid < (BATCH * IMG_W) / 32) {
        // ------------------- Y: cumsum along height (channel 1) -------------
        // Block = 32 columns x 32 segments of 32 rows. Thread (c,s) reads its
        // 32-row segment (per load instr: 2 x 128B fully-used lines), keeps
        // the segment cumsum in registers, shares totals via LDS, adds the
        // exclusive offset, writes back with the same coalesced pattern.
        const int c = threadIdx.x & 31;
        const int s = threadIdx.x >> 5;

        const int col_g = bid * 32 + c;
        const int b     = col_g >> 10;
        const int x     = col_g & (IMG_W - 1);

        const size_t base = (size_t)b * (2 * IMG_W * IMG_W) + (size_t)(IMG_W * IMG_W)
                          + (size_t)x + (size_t)(s * 32) * IMG_W;

        const float* ip = in + base;
        float*       op = out + base;

        float v[32];
        float acc = 0.0f;
        #pragma unroll
        for (int i = 0; i < 32; ++i) {
            acc += ip[(size_t)i * IMG_W];
            v[i] = acc;
        }

        aux[s * 32 + c] = acc;
        __syncthreads();

        // Exclusive prefix over segments for this column (broadcast rows:
        // both half-waves read identical addresses -> conflict-free).
        float off = 0.0f;
        #pragma unroll
        for (int t = 0; t < 31; ++t) {
            const float tv = aux[t * 32 + c];
            off += (t < s) ? tv : 0.0f;
        }

        #pragma unroll
        for (int i = 0; i < 32; ++i) {
            op[(size_t)i * IMG_W] = v[i] + off;
        }
    } else {
        // ------------------- X: cumsum along width (channel 0) --------------
        // One wave per row. Row = 4 chunks of 256 floats; lane l loads
        // float4 #l of the chunk (1 KiB/instruction, perfectly coalesced).
        // Per chunk: 4-elem local scan -> wave shfl_up scan of lane totals ->
        // add exclusive prefix + running carry -> store.
        const int lane = threadIdx.x & 63;
        const int wave = threadIdx.x >> 6;
        const int row  = (bid - (BATCH * IMG_W) / 32) * 16 + wave;  // 0 .. BATCH*IMG_W-1
        const int b    = row >> 10;
        const int y    = row & (IMG_W - 1);

        const size_t base = (size_t)b * (2 * IMG_W * IMG_W) + (size_t)y * IMG_W;
        const float4* ip = (const float4*)(in + base);
        float4*       op = (float4*)(out + base);

        // Hoist all 4 chunk loads (independent of the carry chain).
        float4 a[4];
        #pragma unroll
        for (int q = 0; q < 4; ++q) a[q] = ip[q * 64 + lane];

        float carry = 0.0f;
        #pragma unroll
        for (int q = 0; q < 4; ++q) {
            float4 v = a[q];
            v.y += v.x; v.z += v.y; v.w += v.z;      // local inclusive scan
            const float tot = v.w;
            float sfull = tot;
            #pragma unroll
            for (int d = 1; d < 64; d <<= 1) {        // wave inclusive scan of totals
                float n = __shfl_up(sfull, d);
                if (lane >= d) sfull += n;
            }
            const float add = (sfull - tot) + carry;  // exclusive prefix + carry-in
            v.x += add; v.y += add; v.z += add; v.w += add;
            op[q * 64 + lane] = v;
            carry += __shfl(sfull, 63);               // chunk total, broadcast
        }
    }
}

extern "C" void kernel_launch(void* const* d_in, const int* in_sizes, int n_in,
                              void* d_out, int out_size, void* d_ws, size_t ws_size,
                              hipStream_t stream) {
    const float* in  = (const float*)d_in[0];
    float*       out = (float*)d_out;

    const int y_blocks = (BATCH * IMG_W) / 32;   // 1024
    const int x_blocks = (BATCH * IMG_W) / 16;   // 2048
    sgi_fused_kernel<<<dim3(y_blocks + x_blocks), dim3(1024), 0, stream>>>(in, out);
}